// Round 3
// baseline (350.520 us; speedup 1.0000x reference)
//
#include <hip/hip_runtime.h>

// SSIM loss, round 3: register-resident vertical streaming.
// imgs: (32, 3, 512, 512) fp32. Output: scalar 1 - mean(ssim_map).
//
// Each 64-thread block (1 wave) produces a 64-col x 32-row output strip.
// Input rows stream top->down in chunks of 11 through a small LDS buffer.
// Per input row t (lane = output column):
//   - horizontal Gaussian blur of (x1,x2), (x1^2,x2^2), x1*x2 from 11
//     ds_read_b64 taps (immediate offsets, one shared vaddr)
//   - scatter-add h into 11 in-flight vertical accumulators (registers);
//     chunk loop unrolled by 11 so slot indices (tl - i) mod 11 are
//     compile-time constants -> no shifts, no dynamic indexing, no spill
//   - row j = t-10 completes -> SSIM formula -> lane-local sum
// End: wave reduction + atomicAdd into spread accumulator slots.

#define HH 512
#define WW 512
#define BW 64            // output cols per block (== wavefront)
#define BH 32            // output rows per block
#define SPAIRS 38        // staged float2-pairs per row (cols X0-6 .. X0+69)
#define SCOLS 76
#define CHUNK 11
#define NCHUNK 4         // 44 input rows cover BH+10 = 42
#define NPLANES 96
#define NPIX 25165824.0f
#define NACC 256

typedef float v2f __attribute__((ext_vector_type(2)));
typedef float v4f __attribute__((ext_vector_type(4)));

__global__ __launch_bounds__(64) void ssim_stream_kernel(
    const float* __restrict__ img1, const float* __restrict__ img2,
    float* __restrict__ acc) {
  __shared__ v2f s12[CHUNK][SCOLS];   // (x1,x2) interleaved, 6688 B

  const int lane = threadIdx.x;       // output column within strip
  const int X0 = blockIdx.x * BW;
  const int Y0 = blockIdx.y * BH;
  const size_t pbase = (size_t)blockIdx.z * (HH * WW);

  // Gaussian sigma=1.5, normalized (double-precision derived).
  const float g[11] = {
      1.0283800e-03f, 7.5987600e-03f, 3.6000770e-02f, 1.0936072e-01f,
      2.1300560e-01f, 2.6601170e-01f, 2.1300560e-01f, 1.0936072e-01f,
      3.6000770e-02f, 7.5987600e-03f, 1.0283800e-03f};

  // In-flight vertical accumulators: slot s holds output row j with j%11==s.
  v2f Sm[11];   // (mu1, mu2)
  v2f Sv[11];   // (b11, b22)
  float Sb[11]; // b12
#pragma unroll
  for (int i = 0; i < 11; ++i) {
    Sm[i] = (v2f){0.f, 0.f};
    Sv[i] = (v2f){0.f, 0.f};
    Sb[i] = 0.f;
  }

  const float C1 = 1e-4f;
  const float C2 = 9e-4f;
  float lsum = 0.f;

  for (int k = 0; k < NCHUNK; ++k) {
    __syncthreads();
    // ---- stage input rows t = 11k .. 11k+10 ----
#pragma unroll
    for (int it = 0; it < 7; ++it) {
      int idx = it * 64 + lane;
      if (idx < CHUNK * SPAIRS) {           // 418 pair-slots
        int r = idx / SPAIRS;
        int p = idx - r * SPAIRS;
        int gy = Y0 - 5 + k * CHUNK + r;
        int gx = X0 - 6 + 2 * p;
        bool ok = ((unsigned)gy < (unsigned)HH) && ((unsigned)gx < (unsigned)WW);
        int gyc = min(max(gy, 0), HH - 1);
        int gxc = min(max(gx, 0), WW - 2);  // even, float2-safe
        size_t off = pbase + (size_t)gyc * WW + gxc;
        v2f a = *(const v2f*)(img1 + off);
        v2f b = *(const v2f*)(img2 + off);
        v4f val = ok ? (v4f){a.x, b.x, a.y, b.y} : (v4f){0.f, 0.f, 0.f, 0.f};
        *(v4f*)&s12[r][2 * p] = val;        // 16B-aligned
      }
    }
    __syncthreads();

    // ---- process 11 rows, fully unrolled (static accumulator rotation) ----
#pragma unroll
    for (int tl = 0; tl < CHUNK; ++tl) {
      // horizontal blur: taps at staged cols lane+1 .. lane+11
      v2f a01 = (v2f){0.f, 0.f};
      v2f a23 = (v2f){0.f, 0.f};
      float a4 = 0.f;
#pragma unroll
      for (int dx = 0; dx < 11; ++dx) {
        v2f v = s12[tl][lane + 1 + dx];
        float w = g[dx];
        a01 += w * v;
        v2f sq = v * v;
        a23 += w * sq;
        a4 = __builtin_fmaf(w, v.x * v.y, a4);
      }

      // vertical scatter: input row t contributes w[i] to output row j=t-i
#pragma unroll
      for (int i = 0; i < 11; ++i) {
        const int s = (tl - i + 11) % 11;   // compile-time constant
        float w = g[i];
        Sm[s] += w * a01;
        Sv[s] += w * a23;
        Sb[s] = __builtin_fmaf(w, a4, Sb[s]);
      }

      // output row j = 11k + tl - 10 completes in slot e = (tl+1)%11
      const int e = (tl + 1) % 11;
      int j = k * CHUNK + tl - 10;
      if (j >= 0 && j < BH) {               // wave-uniform branch
        float mu1 = Sm[e].x, mu2 = Sm[e].y;
        float mu1sq = mu1 * mu1;
        float mu2sq = mu2 * mu2;
        float mu12 = mu1 * mu2;
        float sig11 = Sv[e].x - mu1sq;
        float sig22 = Sv[e].y - mu2sq;
        float sig12 = Sb[e] - mu12;
        float num = (2.f * mu12 + C1) * (2.f * sig12 + C2);
        float den = (mu1sq + mu2sq + C1) * (sig11 + sig22 + C2);
        lsum += num * __builtin_amdgcn_rcpf(den);
      }
      // reset slot for reuse by output row j+11 (starts next input row)
      Sm[e] = (v2f){0.f, 0.f};
      Sv[e] = (v2f){0.f, 0.f};
      Sb[e] = 0.f;
    }
  }

  // wave (64-lane) reduction + spread atomics
#pragma unroll
  for (int off = 32; off > 0; off >>= 1)
    lsum += __shfl_down(lsum, off, 64);
  if (lane == 0) {
    int slot = (blockIdx.x + blockIdx.y * 8 + blockIdx.z) & (NACC - 1);
    atomicAdd(acc + slot, lsum);
  }
}

__global__ void ssim_finalize_kernel(const float* __restrict__ acc,
                                     float* __restrict__ out) {
  __shared__ float wsum[4];
  const int tid = threadIdx.x;
  float s = acc[tid];
#pragma unroll
  for (int off = 32; off > 0; off >>= 1)
    s += __shfl_down(s, off, 64);
  if ((tid & 63) == 0) wsum[tid >> 6] = s;
  __syncthreads();
  if (tid == 0)
    out[0] = 1.0f - (wsum[0] + wsum[1] + wsum[2] + wsum[3]) * (1.0f / NPIX);
}

extern "C" void kernel_launch(void* const* d_in, const int* in_sizes, int n_in,
                              void* d_out, int out_size, void* d_ws, size_t ws_size,
                              hipStream_t stream) {
  const float* img1 = (const float*)d_in[0];
  const float* img2 = (const float*)d_in[1];
  float* out = (float*)d_out;
  float* acc = (float*)d_ws;

  hipMemsetAsync(acc, 0, NACC * sizeof(float), stream);

  dim3 grid(WW / BW, HH / BH, NPLANES);   // 8 x 16 x 96 = 12288 blocks
  ssim_stream_kernel<<<grid, BW, 0, stream>>>(img1, img2, acc);
  ssim_finalize_kernel<<<1, NACC, 0, stream>>>(acc, out);
}

// Round 4
// 287.850 us; speedup vs baseline: 1.2177x; 1.2177x over previous
//
#include <hip/hip_runtime.h>

// SSIM loss, round 4: round-2 tiled structure + LDS union (h overlays s12)
// with phase-2 results held in registers, float4 staging, 5 blocks/CU target.
//
// Per block: 32x32 output tile.
//   phase 1: stage 42x48 input region as interleaved (x1,x2) v2f in LDS
//            (float4 global loads, v4f LDS stores; zero-fill = conv zero pad)
//   phase 2: horizontal blur of {x1,x2,x1^2,x2^2,x1*x2} -> REGISTERS
//            (h[r] depends only on s12[r], so after a barrier the h arrays
//             can overwrite the s12 LDS space -> peak LDS 27.7 KB, not 43 KB)
//   phase 3: vertical blur, 4 consecutive rows/thread, sliding 14-tap window,
//            SSIM formula with v_rcp_f32, block reduce, spread atomics.

#define HH 512
#define WW 512
#define TILE 32
#define IN_ROWS 42          // TILE + 10
#define RADX 8              // left halo 8 -> 16B-aligned float4 staging
#define SQUADS 12           // 12 quads of 4 px = 48 staged cols per row
#define S_STRIDE 50         // v2f stride of s12 (padded: row stagger 4 banks)
#define H_STRIDE 33         // padded stride of h arrays
#define NPLANES 96
#define NPIX 25165824.0f
#define NACC 256

// union sizes (bytes)
#define H01_OFF 0           // v2f [42][33] = 11088
#define H23_OFF 11088       // v2f [42][33] = 11088
#define H4_OFF  22176       // float [42][33] = 5544
#define UNION_BYTES 27720   // >= s12: v2f [42][50] = 16800

typedef float v2f __attribute__((ext_vector_type(2)));
typedef float v4f __attribute__((ext_vector_type(4)));

__global__ __launch_bounds__(256, 5) void ssim_fused_kernel(
    const float* __restrict__ img1, const float* __restrict__ img2,
    float* __restrict__ acc) {
  __shared__ __align__(16) char ubuf[UNION_BYTES];
  __shared__ float wsum[4];

  v2f (*s12)[S_STRIDE] = (v2f (*)[S_STRIDE])ubuf;
  v2f (*h01)[H_STRIDE] = (v2f (*)[H_STRIDE])(ubuf + H01_OFF);
  v2f (*h23)[H_STRIDE] = (v2f (*)[H_STRIDE])(ubuf + H23_OFF);
  float (*h4)[H_STRIDE] = (float (*)[H_STRIDE])(ubuf + H4_OFF);

  const int tid = threadIdx.x;
  const int tx = blockIdx.x * TILE;
  const int ty = blockIdx.y * TILE;
  const size_t base = (size_t)blockIdx.z * (HH * WW);

  const float g[11] = {
      1.0283800e-03f, 7.5987600e-03f, 3.6000770e-02f, 1.0936072e-01f,
      2.1300560e-01f, 2.6601170e-01f, 2.1300560e-01f, 1.0936072e-01f,
      3.6000770e-02f, 7.5987600e-03f, 1.0283800e-03f};

  // ---- phase 1: float4 staging, interleave (x1,x2) into LDS ----
  // 42 rows x 12 quads = 504 slots; quads are 16B-aligned in global
  // (gx = tx - 8 + 4p, tx % 32 == 0) and never straddle the image edge.
#pragma unroll
  for (int it = 0; it < 2; ++it) {
    int idx = it * 256 + tid;
    if (idx < IN_ROWS * SQUADS) {
      int r = idx / SQUADS;
      int p = idx - r * SQUADS;
      int gy = ty - 5 + r;
      int gx = tx - RADX + 4 * p;
      v4f A = {0.f, 0.f, 0.f, 0.f}, B = {0.f, 0.f, 0.f, 0.f};
      if ((unsigned)gy < (unsigned)HH && (unsigned)gx < (unsigned)WW) {
        size_t off = base + (size_t)gy * WW + gx;
        A = *(const v4f*)(img1 + off);
        B = *(const v4f*)(img2 + off);
      }
      *(v4f*)&s12[r][4 * p]     = (v4f){A.x, B.x, A.y, B.y};
      *(v4f*)&s12[r][4 * p + 2] = (v4f){A.z, B.z, A.w, B.w};
    }
  }
  __syncthreads();

  // ---- phase 2: horizontal blur -> registers ----
  // 42 rows x 32 cols = 1344 elements; 6 grid-stride iterations.
  v2f p01[6], p23[6];
  float p4[6];
#pragma unroll
  for (int it = 0; it < 6; ++it) {
    int idx = it * 256 + tid;
    if (idx < IN_ROWS * TILE) {
      int r = idx >> 5;
      int c = idx & 31;
      v2f a01 = (v2f){0.f, 0.f};
      v2f a23 = (v2f){0.f, 0.f};
      float a4 = 0.f;
#pragma unroll
      for (int dx = 0; dx < 11; ++dx) {
        // input x = tx + c - 5 + dx -> staged col c + dx + 3
        v2f v = s12[r][c + dx + 3];
        float w = g[dx];
        a01 += w * v;
        v2f sq = v * v;
        a23 += w * sq;
        a4 = __builtin_fmaf(w, v.x * v.y, a4);
      }
      p01[it] = a01;
      p23[it] = a23;
      p4[it] = a4;
    }
  }
  __syncthreads();   // all s12 reads done; safe to overwrite union with h

#pragma unroll
  for (int it = 0; it < 6; ++it) {
    int idx = it * 256 + tid;
    if (idx < IN_ROWS * TILE) {
      int r = idx >> 5;
      int c = idx & 31;
      h01[r][c] = p01[it];
      h23[r][c] = p23[it];
      h4[r][c] = p4[it];
    }
  }
  __syncthreads();

  // ---- phase 3: vertical blur, 4 consecutive rows/thread, sliding window ----
  const float C1 = 1e-4f;
  const float C2 = 9e-4f;
  const int c = tid & 31;
  const int r0 = (tid >> 5) * 4;

  v2f m[4], vv[4];
  float b12[4];
#pragma unroll
  for (int o = 0; o < 4; ++o) {
    m[o] = (v2f){0.f, 0.f};
    vv[o] = (v2f){0.f, 0.f};
    b12[o] = 0.f;
  }

#pragma unroll
  for (int dy = 0; dy < 14; ++dy) {
    v2f a = h01[r0 + dy][c];
    v2f b = h23[r0 + dy][c];
    float d = h4[r0 + dy][c];
#pragma unroll
    for (int o = 0; o < 4; ++o) {
      const int k = dy - o;
      if (k >= 0 && k < 11) {
        float w = g[k];
        m[o] += w * a;
        vv[o] += w * b;
        b12[o] = __builtin_fmaf(w, d, b12[o]);
      }
    }
  }

  float lsum = 0.f;
#pragma unroll
  for (int o = 0; o < 4; ++o) {
    float mu1 = m[o].x, mu2 = m[o].y;
    float mu1sq = mu1 * mu1;
    float mu2sq = mu2 * mu2;
    float mu12 = mu1 * mu2;
    float sig11 = vv[o].x - mu1sq;
    float sig22 = vv[o].y - mu2sq;
    float sig12 = b12[o] - mu12;
    float num = (2.f * mu12 + C1) * (2.f * sig12 + C2);
    float den = (mu1sq + mu2sq + C1) * (sig11 + sig22 + C2);
    lsum += num * __builtin_amdgcn_rcpf(den);
  }

  // wave reduction + one atomic per block into spread slots
#pragma unroll
  for (int off = 32; off > 0; off >>= 1)
    lsum += __shfl_down(lsum, off, 64);
  const int lane = tid & 63;
  const int wid = tid >> 6;
  if (lane == 0) wsum[wid] = lsum;
  __syncthreads();
  if (tid == 0) {
    float b = wsum[0] + wsum[1] + wsum[2] + wsum[3];
    int slot = (blockIdx.x + blockIdx.y * 16 + blockIdx.z) & (NACC - 1);
    atomicAdd(acc + slot, b);
  }
}

__global__ void ssim_finalize_kernel(const float* __restrict__ acc,
                                     float* __restrict__ out) {
  __shared__ float wsum[4];
  const int tid = threadIdx.x;
  float s = acc[tid];
#pragma unroll
  for (int off = 32; off > 0; off >>= 1)
    s += __shfl_down(s, off, 64);
  if ((tid & 63) == 0) wsum[tid >> 6] = s;
  __syncthreads();
  if (tid == 0)
    out[0] = 1.0f - (wsum[0] + wsum[1] + wsum[2] + wsum[3]) * (1.0f / NPIX);
}

extern "C" void kernel_launch(void* const* d_in, const int* in_sizes, int n_in,
                              void* d_out, int out_size, void* d_ws, size_t ws_size,
                              hipStream_t stream) {
  const float* img1 = (const float*)d_in[0];
  const float* img2 = (const float*)d_in[1];
  float* out = (float*)d_out;
  float* acc = (float*)d_ws;

  hipMemsetAsync(acc, 0, NACC * sizeof(float), stream);

  dim3 grid(WW / TILE, HH / TILE, NPLANES);   // 16 x 16 x 96 = 24576
  ssim_fused_kernel<<<grid, 256, 0, stream>>>(img1, img2, acc);
  ssim_finalize_kernel<<<1, NACC, 0, stream>>>(acc, out);
}